// Round 6
// baseline (397.248 us; speedup 1.0000x reference)
//
#include <hip/hip_runtime.h>

#define B_ 128
#define T_ 256
#define H_ 768
#define K_ 64
#define BT_ (B_ * T_)

// ---------------------------------------------------------------------------
// DPP helpers. row_ror:k = ctrl 0x120+k (rotation within 16-lane rows —
// row-LOCAL, no half-wave crossing). Column mapping probed at runtime.
// ---------------------------------------------------------------------------
template <int CTRL>
__device__ __forceinline__ float dpp_mov_f(float x) {
    return __int_as_float(__builtin_amdgcn_update_dpp(
        __float_as_int(x), __float_as_int(x), CTRL, 0xF, 0xF, false));
}
template <int CTRL>
__device__ __forceinline__ int dpp_mov_i(int x) {
    return __builtin_amdgcn_update_dpp(x, x, CTRL, 0xF, 0xF, false);
}
__device__ __forceinline__ float wave_max64(float x) {
    x = fmaxf(x, dpp_mov_f<0x111>(x));  // row_shr:1
    x = fmaxf(x, dpp_mov_f<0x112>(x));  // row_shr:2
    x = fmaxf(x, dpp_mov_f<0x114>(x));  // row_shr:4
    x = fmaxf(x, dpp_mov_f<0x118>(x));  // row_shr:8
    x = fmaxf(x, dpp_mov_f<0x142>(x));  // row_bcast:15
    x = fmaxf(x, dpp_mov_f<0x143>(x));  // row_bcast:31
    return __int_as_float(__builtin_amdgcn_readlane(__float_as_int(x), 63));
}
__device__ __forceinline__ float readlane0_f(float x) {
    return __int_as_float(__builtin_amdgcn_readfirstlane(__float_as_int(x)));
}

// ---------------------------------------------------------------------------
// Kernel A: emissions = hidden @ W + b.  (round-2 version; not the lever.)
// ---------------------------------------------------------------------------
#define BK_ 32
#define BM_ 64
#define P_ 66
__global__ __launch_bounds__(256) void gemm_emis(const float* __restrict__ hidden,
                                                 const float* __restrict__ W,
                                                 const float* __restrict__ bias,
                                                 float* __restrict__ emis) {
    __shared__ float At[BK_ * P_];

    const int tid = threadIdx.x;
    const int lane = tid & 63;
    const int wc = __builtin_amdgcn_readfirstlane((tid >> 6) * 16);
    const int rowbase = blockIdx.x * BM_;
    const int srow = tid >> 2;
    const int scol = (tid & 3) * 8;

    float acc[16];
#pragma unroll
    for (int c = 0; c < 16; ++c) acc[c] = bias[wc + c];

    float4 pf0 = *(const float4*)&hidden[(size_t)(rowbase + srow) * H_ + scol];
    float4 pf1 = *(const float4*)&hidden[(size_t)(rowbase + srow) * H_ + scol + 4];

    for (int kb = 0; kb < H_ / BK_; ++kb) {
        __syncthreads();
        At[(scol + 0) * P_ + srow] = pf0.x;
        At[(scol + 1) * P_ + srow] = pf0.y;
        At[(scol + 2) * P_ + srow] = pf0.z;
        At[(scol + 3) * P_ + srow] = pf0.w;
        At[(scol + 4) * P_ + srow] = pf1.x;
        At[(scol + 5) * P_ + srow] = pf1.y;
        At[(scol + 6) * P_ + srow] = pf1.z;
        At[(scol + 7) * P_ + srow] = pf1.w;
        __syncthreads();
        if (kb + 1 < H_ / BK_) {
            pf0 = *(const float4*)&hidden[(size_t)(rowbase + srow) * H_ +
                                          (kb + 1) * BK_ + scol];
            pf1 = *(const float4*)&hidden[(size_t)(rowbase + srow) * H_ +
                                          (kb + 1) * BK_ + scol + 4];
        }
        const float* Wk = &W[(kb * BK_) * K_ + wc];
#pragma unroll 8
        for (int h = 0; h < BK_; ++h) {
            float a = At[h * P_ + lane];
            float4 w0 = *(const float4*)&Wk[h * K_ + 0];
            float4 w1 = *(const float4*)&Wk[h * K_ + 4];
            float4 w2 = *(const float4*)&Wk[h * K_ + 8];
            float4 w3 = *(const float4*)&Wk[h * K_ + 12];
            acc[0]  += a * w0.x;  acc[1]  += a * w0.y;
            acc[2]  += a * w0.z;  acc[3]  += a * w0.w;
            acc[4]  += a * w1.x;  acc[5]  += a * w1.y;
            acc[6]  += a * w1.z;  acc[7]  += a * w1.w;
            acc[8]  += a * w2.x;  acc[9]  += a * w2.y;
            acc[10] += a * w2.z;  acc[11] += a * w2.w;
            acc[12] += a * w3.x;  acc[13] += a * w3.y;
            acc[14] += a * w3.z;  acc[15] += a * w3.w;
        }
    }

    float* e = &emis[(size_t)(rowbase + lane) * K_ + wc];
#pragma unroll
    for (int q = 0; q < 4; ++q)
        *(float4*)&e[q * 4] = make_float4(acc[q * 4], acc[q * 4 + 1],
                                          acc[q * 4 + 2], acc[q * 4 + 3]);
}

// ---------------------------------------------------------------------------
// Kernel B: fused CRF.  Round 6: ROW-LOCAL exchange. Evidence r0/r3/r4/r5:
// every half-wave-crossing lane op (readlane, wave_ror, LDS+barrier) costs
// ~15-20cy and 64/step pin the scan at ~140us regardless of packaging. This
// round uses only THREE boundary-crossing ops per step (shfl_xor 16/32 to
// give every row all 4 pages of p) + 60 row_ror:k rotations (row-local DPP,
// hypothesized full-rate, all independent at depth 1) + 64 fma/max against a
// pre-gathered per-lane table Et[page][k]. Source coverage: i = 16*(row^m) +
// ((col+off[k])&15), m<4, k<16 — exact, probed off[k] per rotation. Viterbi
// max-set identical -> bit-identical decode; fwd dot reordered (r4/r5 both
// passed absmax 0.0). Shell/backtrack verbatim r0.
// ---------------------------------------------------------------------------
__global__ __launch_bounds__(128, 1) void crf_kernel(const float* __restrict__ emis,
                                                     const int* __restrict__ masks,
                                                     const int* __restrict__ target,
                                                     const float* __restrict__ trans,
                                                     float* __restrict__ out) {
    __shared__ __align__(16) float ebuf[T_ * K_];   // 64 KB emissions for batch b
    __shared__ __align__(16) float vbuf[T_ * K_];   // 64 KB viterbi v-history
    __shared__ float tbuf[K_ * 65];                 // padded trans rows (backtrack)

    const int tid = threadIdx.x;
    const int lane = tid & 63;
    const int b = blockIdx.x;
    const float* eb = emis + (size_t)b * (T_ * K_);

    // stage emissions: 4096 float4s over 128 threads
    {
        const float4* src = (const float4*)eb;
        float4* dst = (float4*)ebuf;
#pragma unroll
        for (int k = 0; k < 32; ++k) dst[tid + k * 128] = src[tid + k * 128];
    }
    int sl = 0;
#pragma unroll
    for (int k = 0; k < 4; ++k) sl += masks[b * T_ + lane + k * 64];
#pragma unroll
    for (int m = 32; m; m >>= 1) sl += __shfl_xor(sl, m, 64);
    const int seq_len = sl;

    // probe row_ror:k column offsets (uniform per wave): after row_ror:k,
    // lane (row, c) holds the value from lane (row, (c + off[k]) & 15).
    int off[16];
    off[0] = 0;
#define PR(k) off[k] = __builtin_amdgcn_readfirstlane(dpp_mov_i<0x120 + (k)>(lane)) & 15;
    PR(1) PR(2) PR(3) PR(4) PR(5) PR(6) PR(7) PR(8)
    PR(9) PR(10) PR(11) PR(12) PR(13) PR(14) PR(15)
#undef PR
    const int rw = lane >> 4;   // row (0..3)
    const int cl = lane & 15;   // col in row

    __syncthreads();

    if (tid < 64) {
        // ================= forward (wave 0), delayed normalization ==========
        // Et[m][k] = exp(trans[16*(rw^m) + ((cl+off[k])&15)][lane])
        float Et[4][16];
#pragma unroll
        for (int m = 0; m < 4; ++m)
#pragma unroll
            for (int k = 0; k < 16; ++k) {
                int i = 16 * (rw ^ m) + ((cl + off[k]) & 15);
                Et[m][k] = __expf(trans[i * K_ + lane]);
            }

        float e_c = ebuf[lane];
        float e00 = readlane0_f(e_c);
        float p = __expf(e_c - e00);     // e^{alpha_0} = p * e^C
        float C = e00;
        float logD0prev = 0.f;
        float e_n = ebuf[K_ + lane];
        float en0 = readlane0_f(e_n);
        float xg = __expf(e_n - en0);    // x * g

        for (int t = 1; t < T_; ++t) {
            float e_f = (t < T_ - 1) ? ebuf[(t + 1) * K_ + lane] : 0.f;
            // 3 boundary-crossing ops: rows get all 4 pages of p
            float y1 = __shfl_xor(p, 16, 64);   // page rw^1
            float y2 = __shfl_xor(p, 32, 64);   // page rw^2
            float y3 = __shfl_xor(y1, 32, 64);  // page rw^3
            float a0 = p  * Et[0][0];
            float a1 = y1 * Et[1][0];
            float a2 = y2 * Et[2][0];
            float a3 = y3 * Et[3][0];
            // 60 independent row-local rotations (depth 1 each) + 60 fma
#define RK(k)                                                          \
            a0 = fmaf(dpp_mov_f<0x120 + (k)>(p),  Et[0][(k)], a0);     \
            a1 = fmaf(dpp_mov_f<0x120 + (k)>(y1), Et[1][(k)], a1);     \
            a2 = fmaf(dpp_mov_f<0x120 + (k)>(y2), Et[2][(k)], a2);     \
            a3 = fmaf(dpp_mov_f<0x120 + (k)>(y3), Et[3][(k)], a3);
            RK(1) RK(2) RK(3) RK(4) RK(5) RK(6) RK(7) RK(8)
            RK(9) RK(10) RK(11) RK(12) RK(13) RK(14) RK(15)
#undef RK
            float D = (a0 + a1) + (a2 + a3);
            float pnew = D * xg;         // only on-chain op after the dot
            if (t < seq_len) { p = pnew; C += en0 + logD0prev; }
            // off-chain prep for next step
            float D0 = readlane0_f(D);
            logD0prev = __logf(D0);
            float gn = __fdividef(1.f, D0);
            en0 = readlane0_f(e_f);
            xg = __expf(e_f - en0) * gn;
            e_n = e_f;
        }
        float rs = p;
#pragma unroll
        for (int m = 32; m; m >>= 1) rs += __shfl_xor(rs, m, 64);
        float log_norm = C + __logf(rs);

        // ---------------- sequence score ----------------
        float sc = 0.f;
#pragma unroll
        for (int k = 0; k < 4; ++k) {
            int t = lane + k * 64;
            if (t < seq_len) {
                int tg = target[b * T_ + t];
                sc += ebuf[t * K_ + tg];
                if (t >= 1) sc += trans[target[b * T_ + t - 1] * K_ + tg];
            }
        }
#pragma unroll
        for (int m = 32; m; m >>= 1) sc += __shfl_xor(sc, m, 64);
        if (lane == 0) out[BT_ + b] = sc - log_norm;
    } else {
        // ================= Viterbi (wave 1): row-local max-plus =============
        float Tt[4][16];
#pragma unroll
        for (int m = 0; m < 4; ++m)
#pragma unroll
            for (int k = 0; k < 16; ++k) {
                int i = 16 * (rw ^ m) + ((cl + off[k]) & 15);
                Tt[m][k] = trans[i * K_ + lane];
            }
        for (int idx = lane; idx < K_ * K_; idx += 64)
            tbuf[(idx >> 6) * 65 + (idx & 63)] = trans[idx];

        float v = ebuf[lane];
        vbuf[lane] = v;
        float e_n = ebuf[K_ + lane];
        for (int t = 1; t < T_; ++t) {
            float e_f = (t < T_ - 1) ? ebuf[(t + 1) * K_ + lane] : 0.f;
            float y1 = __shfl_xor(v, 16, 64);
            float y2 = __shfl_xor(v, 32, 64);
            float y3 = __shfl_xor(y1, 32, 64);
            float m0 = v  + Tt[0][0];
            float m1 = y1 + Tt[1][0];
            float m2 = y2 + Tt[2][0];
            float m3 = y3 + Tt[3][0];
#define VK(k)                                                            \
            m0 = fmaxf(m0, dpp_mov_f<0x120 + (k)>(v)  + Tt[0][(k)]);     \
            m1 = fmaxf(m1, dpp_mov_f<0x120 + (k)>(y1) + Tt[1][(k)]);     \
            m2 = fmaxf(m2, dpp_mov_f<0x120 + (k)>(y2) + Tt[2][(k)]);     \
            m3 = fmaxf(m3, dpp_mov_f<0x120 + (k)>(y3) + Tt[3][(k)]);
            VK(1) VK(2) VK(3) VK(4) VK(5) VK(6) VK(7) VK(8)
            VK(9) VK(10) VK(11) VK(12) VK(13) VK(14) VK(15)
#undef VK
            float M = fmaxf(fmaxf(m0, m1), fmaxf(m2, m3));
            float vn = M + e_n;
            if (t < seq_len) v = vn;
            vbuf[t * K_ + lane] = v;   // off-chain ds_write (history)
            e_n = e_f;
        }

        // last tag: first index of max over lanes (np.argmax tie rule)
        float M = wave_max64(v);
        unsigned long long ball = __ballot(v >= M);
        int tag = (int)__builtin_ctzll(ball);

        int path[4];
#pragma unroll
        for (int k = 0; k < 4; ++k) path[k] = 0;
        if (lane == ((T_ - 1) & 63)) path[(T_ - 1) >> 6] = tag;

        float vpre = vbuf[(T_ - 2) * K_ + lane];
        for (int t = T_ - 1; t >= 1; --t) {
            float vnext = (t >= 2) ? vbuf[(t - 2) * K_ + lane] : 0.f;
            if (t < seq_len) {
                float s = vpre + tbuf[lane * 65 + tag];
                float Ms = wave_max64(s);
                unsigned long long bl = __ballot(s >= Ms);
                tag = (int)__builtin_ctzll(bl);
            }
            int pidx = t - 1;
            if (lane == (pidx & 63)) path[pidx >> 6] = tag;
            vpre = vnext;
        }
#pragma unroll
        for (int k = 0; k < 4; ++k) {
            int t = lane + k * 64;
            out[b * T_ + t] = (t < seq_len) ? (float)path[k] : 0.f;
        }
    }
}

// ---------------------------------------------------------------------------
extern "C" void kernel_launch(void* const* d_in, const int* in_sizes, int n_in,
                              void* d_out, int out_size, void* d_ws, size_t ws_size,
                              hipStream_t stream) {
    const float* hidden = (const float*)d_in[0];
    const int* masks    = (const int*)d_in[1];
    const int* target   = (const int*)d_in[2];
    const float* W      = (const float*)d_in[3];
    const float* bias   = (const float*)d_in[4];
    const float* trans  = (const float*)d_in[5];
    float* out = (float*)d_out;
    float* emis = (float*)d_ws;

    gemm_emis<<<dim3(BT_ / BM_), dim3(256), 0, stream>>>(hidden, W, bias, emis);
    crf_kernel<<<dim3(B_), dim3(128), 0, stream>>>(emis, masks, target, trans, out);
}

// Round 7
// 375.649 us; speedup vs baseline: 1.0575x; 1.0575x over previous
//
#include <hip/hip_runtime.h>

#define B_ 128
#define T_ 256
#define H_ 768
#define K_ 64
#define BT_ (B_ * T_)

// ---------------------------------------------------------------------------
// DPP helpers: wave-wide max in ~6 VALU ops (row_shr/bcast ladder).
// ---------------------------------------------------------------------------
template <int CTRL>
__device__ __forceinline__ float dpp_mov_f(float x) {
    return __int_as_float(__builtin_amdgcn_update_dpp(
        __float_as_int(x), __float_as_int(x), CTRL, 0xF, 0xF, false));
}
__device__ __forceinline__ float wave_max64(float x) {
    x = fmaxf(x, dpp_mov_f<0x111>(x));  // row_shr:1
    x = fmaxf(x, dpp_mov_f<0x112>(x));  // row_shr:2
    x = fmaxf(x, dpp_mov_f<0x114>(x));  // row_shr:4
    x = fmaxf(x, dpp_mov_f<0x118>(x));  // row_shr:8
    x = fmaxf(x, dpp_mov_f<0x142>(x));  // row_bcast:15
    x = fmaxf(x, dpp_mov_f<0x143>(x));  // row_bcast:31
    return __int_as_float(__builtin_amdgcn_readlane(__float_as_int(x), 63));
}
__device__ __forceinline__ float readlane0_f(float x) {
    return __int_as_float(__builtin_amdgcn_readfirstlane(__float_as_int(x)));
}
template <int I>
__device__ __forceinline__ float readlane_f(float x) {
    return __int_as_float(__builtin_amdgcn_readlane(__float_as_int(x), I));
}

// ---------------------------------------------------------------------------
// Kernel A: emissions = hidden @ W + b.  (round-2 version; not the lever.)
// ---------------------------------------------------------------------------
#define BK_ 32
#define BM_ 64
#define P_ 66
__global__ __launch_bounds__(256) void gemm_emis(const float* __restrict__ hidden,
                                                 const float* __restrict__ W,
                                                 const float* __restrict__ bias,
                                                 float* __restrict__ emis) {
    __shared__ float At[BK_ * P_];

    const int tid = threadIdx.x;
    const int lane = tid & 63;
    const int wc = __builtin_amdgcn_readfirstlane((tid >> 6) * 16);
    const int rowbase = blockIdx.x * BM_;
    const int srow = tid >> 2;
    const int scol = (tid & 3) * 8;

    float acc[16];
#pragma unroll
    for (int c = 0; c < 16; ++c) acc[c] = bias[wc + c];

    float4 pf0 = *(const float4*)&hidden[(size_t)(rowbase + srow) * H_ + scol];
    float4 pf1 = *(const float4*)&hidden[(size_t)(rowbase + srow) * H_ + scol + 4];

    for (int kb = 0; kb < H_ / BK_; ++kb) {
        __syncthreads();
        At[(scol + 0) * P_ + srow] = pf0.x;
        At[(scol + 1) * P_ + srow] = pf0.y;
        At[(scol + 2) * P_ + srow] = pf0.z;
        At[(scol + 3) * P_ + srow] = pf0.w;
        At[(scol + 4) * P_ + srow] = pf1.x;
        At[(scol + 5) * P_ + srow] = pf1.y;
        At[(scol + 6) * P_ + srow] = pf1.z;
        At[(scol + 7) * P_ + srow] = pf1.w;
        __syncthreads();
        if (kb + 1 < H_ / BK_) {
            pf0 = *(const float4*)&hidden[(size_t)(rowbase + srow) * H_ +
                                          (kb + 1) * BK_ + scol];
            pf1 = *(const float4*)&hidden[(size_t)(rowbase + srow) * H_ +
                                          (kb + 1) * BK_ + scol + 4];
        }
        const float* Wk = &W[(kb * BK_) * K_ + wc];
#pragma unroll 8
        for (int h = 0; h < BK_; ++h) {
            float a = At[h * P_ + lane];
            float4 w0 = *(const float4*)&Wk[h * K_ + 0];
            float4 w1 = *(const float4*)&Wk[h * K_ + 4];
            float4 w2 = *(const float4*)&Wk[h * K_ + 8];
            float4 w3 = *(const float4*)&Wk[h * K_ + 12];
            acc[0]  += a * w0.x;  acc[1]  += a * w0.y;
            acc[2]  += a * w0.z;  acc[3]  += a * w0.w;
            acc[4]  += a * w1.x;  acc[5]  += a * w1.y;
            acc[6]  += a * w1.z;  acc[7]  += a * w1.w;
            acc[8]  += a * w2.x;  acc[9]  += a * w2.y;
            acc[10] += a * w2.z;  acc[11] += a * w2.w;
            acc[12] += a * w3.x;  acc[13] += a * w3.y;
            acc[14] += a * w3.z;  acc[15] += a * w3.w;
        }
    }

    float* e = &emis[(size_t)(rowbase + lane) * K_ + wc];
#pragma unroll
    for (int q = 0; q < 4; ++q)
        *(float4*)&e[q * 4] = make_float4(acc[q * 4], acc[q * 4 + 1],
                                          acc[q * 4 + 2], acc[q * 4 + 3]);
}

// ---------------------------------------------------------------------------
// Kernel B: fused CRF.  Round 7: TWO-PIPE HYBRID exchange. Ledger: readlane
// 1330 cy/step, LDS+barrier 1320, wave-DPP 1340, row-DPP 1700, serialized LDS
// 1500 — every single-pipe mechanism pays its full serial cost. This round
// splits the 64-value broadcast across BOTH pipes: i=0..23 via readlane
// (VALU, ~380cy) while i=24..63 arrive via 10 broadcast ds_read_b128 (DS
// pipe) issued at loop top from a vector written at the END of the previous
// step — DS latency hides under the readlane stream. No barrier: same-wave
// DS ops are in-order, and the reads alias the prior write (same row), so
// the compiler cannot hoist them. Viterbi's history write vbuf[t*K+lane] IS
// its exchange vector (read row t-1 back as float4). Viterbi max-set
// identical -> bit-exact decode; forward dot regrouped (tolerated, r4-r6
// all absmax 0.0). Shell/backtrack verbatim r0.
// ---------------------------------------------------------------------------
__global__ __launch_bounds__(128, 1) void crf_kernel(const float* __restrict__ emis,
                                                     const int* __restrict__ masks,
                                                     const int* __restrict__ target,
                                                     const float* __restrict__ trans,
                                                     float* __restrict__ out) {
    __shared__ __align__(16) float ebuf[T_ * K_];   // 64 KB emissions for batch b
    __shared__ __align__(16) float vbuf[T_ * K_];   // 64 KB viterbi v-history
    __shared__ float tbuf[K_ * 65];                 // padded trans rows (backtrack)
    __shared__ __align__(16) float pexch[68];       // forward p exchange vector

    const int tid = threadIdx.x;
    const int lane = tid & 63;
    const int b = blockIdx.x;
    const float* eb = emis + (size_t)b * (T_ * K_);

    // stage emissions: 4096 float4s over 128 threads
    {
        const float4* src = (const float4*)eb;
        float4* dst = (float4*)ebuf;
#pragma unroll
        for (int k = 0; k < 32; ++k) dst[tid + k * 128] = src[tid + k * 128];
    }
    int sl = 0;
#pragma unroll
    for (int k = 0; k < 4; ++k) sl += masks[b * T_ + lane + k * 64];
#pragma unroll
    for (int m = 32; m; m >>= 1) sl += __shfl_xor(sl, m, 64);
    const int seq_len = sl;
    __syncthreads();

    if (tid < 64) {
        // ================= forward (wave 0), delayed normalization ==========
        float Ecol[64];
#pragma unroll
        for (int i = 0; i < 64; ++i) Ecol[i] = __expf(trans[i * K_ + lane]);

        float e_c = ebuf[lane];
        float e00 = readlane0_f(e_c);
        float p = __expf(e_c - e00);     // e^{alpha_0} = p * e^C
        float C = e00;
        float logD0prev = 0.f;
        float e_n = ebuf[K_ + lane];
        float en0 = readlane0_f(e_n);
        float xg = __expf(e_n - en0);    // x * g
        pexch[lane] = p;                 // publish p_0 (same-wave DS order)

        for (int t = 1; t < T_; ++t) {
            // DS-pipe portion: issue broadcast reads of p[24..63] FIRST.
            // These follow last step's pexch[lane] write in the in-order DS
            // pipe; latency hides under the readlane block below.
            float4 L[10];
#pragma unroll
            for (int k = 0; k < 10; ++k)
                L[k] = *(const float4*)&pexch[24 + 4 * k];
            float e_f = (t < T_ - 1) ? ebuf[(t + 1) * K_ + lane] : 0.f;

            // VALU-pipe portion: i = 0..23 via readlane (covers DS latency)
            float a0 = 0.f, a1 = 0.f, a2 = 0.f, a3 = 0.f;
#define RL4(i)                                                      \
            a0 = fmaf(readlane_f<(i) + 0>(p), Ecol[(i) + 0], a0);   \
            a1 = fmaf(readlane_f<(i) + 1>(p), Ecol[(i) + 1], a1);   \
            a2 = fmaf(readlane_f<(i) + 2>(p), Ecol[(i) + 2], a2);   \
            a3 = fmaf(readlane_f<(i) + 3>(p), Ecol[(i) + 3], a3);
            RL4(0) RL4(4) RL4(8) RL4(12) RL4(16) RL4(20)
#undef RL4
            // LDS-sourced portion: i = 24..63
#pragma unroll
            for (int k = 0; k < 10; ++k) {
                a0 = fmaf(L[k].x, Ecol[24 + 4 * k + 0], a0);
                a1 = fmaf(L[k].y, Ecol[24 + 4 * k + 1], a1);
                a2 = fmaf(L[k].z, Ecol[24 + 4 * k + 2], a2);
                a3 = fmaf(L[k].w, Ecol[24 + 4 * k + 3], a3);
            }
            float D = (a0 + a1) + (a2 + a3);
            float pnew = D * xg;         // only on-chain op after the dot
            if (t < seq_len) { p = pnew; C += en0 + logD0prev; }
            pexch[lane] = p;             // publish for next step's reads
            // off-chain prep for next step
            float D0 = readlane0_f(D);
            logD0prev = __logf(D0);
            float gn = __fdividef(1.f, D0);
            en0 = readlane0_f(e_f);
            xg = __expf(e_f - en0) * gn;
            e_n = e_f;
        }
        float rs = p;
#pragma unroll
        for (int m = 32; m; m >>= 1) rs += __shfl_xor(rs, m, 64);
        float log_norm = C + __logf(rs);

        // ---------------- sequence score ----------------
        float sc = 0.f;
#pragma unroll
        for (int k = 0; k < 4; ++k) {
            int t = lane + k * 64;
            if (t < seq_len) {
                int tg = target[b * T_ + t];
                sc += ebuf[t * K_ + tg];
                if (t >= 1) sc += trans[target[b * T_ + t - 1] * K_ + tg];
            }
        }
#pragma unroll
        for (int m = 32; m; m >>= 1) sc += __shfl_xor(sc, m, 64);
        if (lane == 0) out[BT_ + b] = sc - log_norm;
    } else {
        // ================= Viterbi (wave 1): hybrid max-plus ================
        float Tcol[64];
#pragma unroll
        for (int i = 0; i < 64; ++i) Tcol[i] = trans[i * K_ + lane];
        for (int idx = lane; idx < K_ * K_; idx += 64)
            tbuf[(idx >> 6) * 65 + (idx & 63)] = trans[idx];

        float v = ebuf[lane];
        vbuf[lane] = v;                  // history write == exchange publish
        float e_n = ebuf[K_ + lane];
        for (int t = 1; t < T_; ++t) {
            // DS-pipe portion: broadcast-read v[24..63] of row t-1 (written
            // at the end of the previous iteration; same-row alias ensures
            // program order; latency hides under the readlane block).
            float4 L[10];
            const float4* vprev = (const float4*)&vbuf[(t - 1) * K_];
#pragma unroll
            for (int k = 0; k < 10; ++k) L[k] = vprev[6 + k];
            float e_f = (t < T_ - 1) ? ebuf[(t + 1) * K_ + lane] : 0.f;

            float m0 = -3.4e38f, m1 = -3.4e38f, m2 = -3.4e38f, m3 = -3.4e38f;
#define VL4(i)                                                        \
            m0 = fmaxf(m0, readlane_f<(i) + 0>(v) + Tcol[(i) + 0]);   \
            m1 = fmaxf(m1, readlane_f<(i) + 1>(v) + Tcol[(i) + 1]);   \
            m2 = fmaxf(m2, readlane_f<(i) + 2>(v) + Tcol[(i) + 2]);   \
            m3 = fmaxf(m3, readlane_f<(i) + 3>(v) + Tcol[(i) + 3]);
            VL4(0) VL4(4) VL4(8) VL4(12) VL4(16) VL4(20)
#undef VL4
#pragma unroll
            for (int k = 0; k < 10; ++k) {
                m0 = fmaxf(m0, L[k].x + Tcol[24 + 4 * k + 0]);
                m1 = fmaxf(m1, L[k].y + Tcol[24 + 4 * k + 1]);
                m2 = fmaxf(m2, L[k].z + Tcol[24 + 4 * k + 2]);
                m3 = fmaxf(m3, L[k].w + Tcol[24 + 4 * k + 3]);
            }
            float M = fmaxf(fmaxf(m0, m1), fmaxf(m2, m3));
            float vn = M + e_n;
            if (t < seq_len) v = vn;
            vbuf[t * K_ + lane] = v;   // history write == next-step publish
            e_n = e_f;
        }

        // last tag: first index of max over lanes (np.argmax tie rule)
        float M = wave_max64(v);
        unsigned long long ball = __ballot(v >= M);
        int tag = (int)__builtin_ctzll(ball);

        int path[4];
#pragma unroll
        for (int k = 0; k < 4; ++k) path[k] = 0;
        if (lane == ((T_ - 1) & 63)) path[(T_ - 1) >> 6] = tag;

        float vpre = vbuf[(T_ - 2) * K_ + lane];
        for (int t = T_ - 1; t >= 1; --t) {
            float vnext = (t >= 2) ? vbuf[(t - 2) * K_ + lane] : 0.f;
            if (t < seq_len) {
                float s = vpre + tbuf[lane * 65 + tag];
                float Ms = wave_max64(s);
                unsigned long long bl = __ballot(s >= Ms);
                tag = (int)__builtin_ctzll(bl);
            }
            int pidx = t - 1;
            if (lane == (pidx & 63)) path[pidx >> 6] = tag;
            vpre = vnext;
        }
#pragma unroll
        for (int k = 0; k < 4; ++k) {
            int t = lane + k * 64;
            out[b * T_ + t] = (t < seq_len) ? (float)path[k] : 0.f;
        }
    }
}

// ---------------------------------------------------------------------------
extern "C" void kernel_launch(void* const* d_in, const int* in_sizes, int n_in,
                              void* d_out, int out_size, void* d_ws, size_t ws_size,
                              hipStream_t stream) {
    const float* hidden = (const float*)d_in[0];
    const int* masks    = (const int*)d_in[1];
    const int* target   = (const int*)d_in[2];
    const float* W      = (const float*)d_in[3];
    const float* bias   = (const float*)d_in[4];
    const float* trans  = (const float*)d_in[5];
    float* out = (float*)d_out;
    float* emis = (float*)d_ws;

    gemm_emis<<<dim3(BT_ / BM_), dim3(256), 0, stream>>>(hidden, W, bias, emis);
    crf_kernel<<<dim3(B_), dim3(128), 0, stream>>>(emis, masks, target, trans, out);
}

// Round 8
// 373.054 us; speedup vs baseline: 1.0649x; 1.0070x over previous
//
#include <hip/hip_runtime.h>

#define B_ 128
#define T_ 256
#define H_ 768
#define K_ 64
#define BT_ (B_ * T_)

// ---------------------------------------------------------------------------
// DPP helpers: wave-wide max in ~6 VALU ops (row_shr/bcast ladder).
// ---------------------------------------------------------------------------
template <int CTRL>
__device__ __forceinline__ float dpp_mov_f(float x) {
    return __int_as_float(__builtin_amdgcn_update_dpp(
        __float_as_int(x), __float_as_int(x), CTRL, 0xF, 0xF, false));
}
__device__ __forceinline__ float wave_max64(float x) {
    x = fmaxf(x, dpp_mov_f<0x111>(x));  // row_shr:1
    x = fmaxf(x, dpp_mov_f<0x112>(x));  // row_shr:2
    x = fmaxf(x, dpp_mov_f<0x114>(x));  // row_shr:4
    x = fmaxf(x, dpp_mov_f<0x118>(x));  // row_shr:8
    x = fmaxf(x, dpp_mov_f<0x142>(x));  // row_bcast:15
    x = fmaxf(x, dpp_mov_f<0x143>(x));  // row_bcast:31
    return __int_as_float(__builtin_amdgcn_readlane(__float_as_int(x), 63));
}
__device__ __forceinline__ float readlane0_f(float x) {
    return __int_as_float(__builtin_amdgcn_readfirstlane(__float_as_int(x)));
}
template <int I>
__device__ __forceinline__ float readlane_f(float x) {
    return __int_as_float(__builtin_amdgcn_readlane(__float_as_int(x), I));
}

// ---------------------------------------------------------------------------
// Kernel A: emissions = hidden @ W + b.  (round-2 version; not the lever.)
// ---------------------------------------------------------------------------
#define BK_ 32
#define BM_ 64
#define P_ 66
__global__ __launch_bounds__(256) void gemm_emis(const float* __restrict__ hidden,
                                                 const float* __restrict__ W,
                                                 const float* __restrict__ bias,
                                                 float* __restrict__ emis) {
    __shared__ float At[BK_ * P_];

    const int tid = threadIdx.x;
    const int lane = tid & 63;
    const int wc = __builtin_amdgcn_readfirstlane((tid >> 6) * 16);
    const int rowbase = blockIdx.x * BM_;
    const int srow = tid >> 2;
    const int scol = (tid & 3) * 8;

    float acc[16];
#pragma unroll
    for (int c = 0; c < 16; ++c) acc[c] = bias[wc + c];

    float4 pf0 = *(const float4*)&hidden[(size_t)(rowbase + srow) * H_ + scol];
    float4 pf1 = *(const float4*)&hidden[(size_t)(rowbase + srow) * H_ + scol + 4];

    for (int kb = 0; kb < H_ / BK_; ++kb) {
        __syncthreads();
        At[(scol + 0) * P_ + srow] = pf0.x;
        At[(scol + 1) * P_ + srow] = pf0.y;
        At[(scol + 2) * P_ + srow] = pf0.z;
        At[(scol + 3) * P_ + srow] = pf0.w;
        At[(scol + 4) * P_ + srow] = pf1.x;
        At[(scol + 5) * P_ + srow] = pf1.y;
        At[(scol + 6) * P_ + srow] = pf1.z;
        At[(scol + 7) * P_ + srow] = pf1.w;
        __syncthreads();
        if (kb + 1 < H_ / BK_) {
            pf0 = *(const float4*)&hidden[(size_t)(rowbase + srow) * H_ +
                                          (kb + 1) * BK_ + scol];
            pf1 = *(const float4*)&hidden[(size_t)(rowbase + srow) * H_ +
                                          (kb + 1) * BK_ + scol + 4];
        }
        const float* Wk = &W[(kb * BK_) * K_ + wc];
#pragma unroll 8
        for (int h = 0; h < BK_; ++h) {
            float a = At[h * P_ + lane];
            float4 w0 = *(const float4*)&Wk[h * K_ + 0];
            float4 w1 = *(const float4*)&Wk[h * K_ + 4];
            float4 w2 = *(const float4*)&Wk[h * K_ + 8];
            float4 w3 = *(const float4*)&Wk[h * K_ + 12];
            acc[0]  += a * w0.x;  acc[1]  += a * w0.y;
            acc[2]  += a * w0.z;  acc[3]  += a * w0.w;
            acc[4]  += a * w1.x;  acc[5]  += a * w1.y;
            acc[6]  += a * w1.z;  acc[7]  += a * w1.w;
            acc[8]  += a * w2.x;  acc[9]  += a * w2.y;
            acc[10] += a * w2.z;  acc[11] += a * w2.w;
            acc[12] += a * w3.x;  acc[13] += a * w3.y;
            acc[14] += a * w3.z;  acc[15] += a * w3.w;
        }
    }

    float* e = &emis[(size_t)(rowbase + lane) * K_ + wc];
#pragma unroll
    for (int q = 0; q < 4; ++q)
        *(float4*)&e[q * 4] = make_float4(acc[q * 4], acc[q * 4 + 1],
                                          acc[q * 4 + 2], acc[q * 4 + 3]);
}

// ---------------------------------------------------------------------------
// Kernel B: fused CRF.  Round 8: PIPELINED off-chain exchange. Ledger
// (cy/step): readlane 1330 / LDS+barrier 1320 / wave-DPP 1340 / row-DPP 1700
// / intra-step hybrid 1470 — every variant kept the 64-wide exchange ON the
// per-step dependency chain. This round pipelines it OFF: at the end of step
// t, publish p_t (ds_write) and immediately ISSUE 14 ds_read_b128 for step
// t+1 into loop-carried VGPRs; they are consumed only after next iteration's
// prep + 8-readlane stub (~300cy window >> ~150cy LDS latency) so the
// s_waitcnt is free. Program-order aliasing (pexch[lane] vs pexch[8..63])
// pins issue order; in-order DS pipe returns the new values; single wave ->
// no barrier. Only 8/64 sources remain on-chain (readlane); 56 arrive as
// plain VGPR fma/max (SGPR-free, full rate). Viterbi: history write IS the
// publish (read row t back as quads). Viterbi max-set identical -> bit-exact
// decode; forward dot regrouped (tolerated, r4-r7 all absmax 0.0).
// Shell/backtrack verbatim r0.
// ---------------------------------------------------------------------------
__global__ __launch_bounds__(128, 1) void crf_kernel(const float* __restrict__ emis,
                                                     const int* __restrict__ masks,
                                                     const int* __restrict__ target,
                                                     const float* __restrict__ trans,
                                                     float* __restrict__ out) {
    __shared__ __align__(16) float ebuf[T_ * K_];   // 64 KB emissions for batch b
    __shared__ __align__(16) float vbuf[T_ * K_];   // 64 KB viterbi v-history
    __shared__ float tbuf[K_ * 65];                 // padded trans rows (backtrack)
    __shared__ __align__(16) float pexch[K_];       // forward p exchange vector

    const int tid = threadIdx.x;
    const int lane = tid & 63;
    const int b = blockIdx.x;
    const float* eb = emis + (size_t)b * (T_ * K_);

    // stage emissions: 4096 float4s over 128 threads
    {
        const float4* src = (const float4*)eb;
        float4* dst = (float4*)ebuf;
#pragma unroll
        for (int k = 0; k < 32; ++k) dst[tid + k * 128] = src[tid + k * 128];
    }
    int sl = 0;
#pragma unroll
    for (int k = 0; k < 4; ++k) sl += masks[b * T_ + lane + k * 64];
#pragma unroll
    for (int m = 32; m; m >>= 1) sl += __shfl_xor(sl, m, 64);
    const int seq_len = sl;
    __syncthreads();

    if (tid < 64) {
        // ================= forward (wave 0), delayed normalization ==========
        float Ecol[64];
#pragma unroll
        for (int i = 0; i < 64; ++i) Ecol[i] = __expf(trans[i * K_ + lane]);

        float e_c = ebuf[lane];
        float e00 = readlane0_f(e_c);
        float p = __expf(e_c - e00);     // e^{alpha_0} = p * e^C
        float C = e00;
        float logD0prev = 0.f;
        float e_n = ebuf[K_ + lane];
        float en0 = readlane0_f(e_n);
        float xg = __expf(e_n - en0);    // x * g

        // publish p_0 and pre-issue the step-1 exchange reads
        pexch[lane] = p;
        float4 Lp[14];
#pragma unroll
        for (int k = 0; k < 14; ++k) Lp[k] = *(const float4*)&pexch[8 + 4 * k];

        for (int t = 1; t < T_; ++t) {
            float e_f = (t < T_ - 1) ? ebuf[(t + 1) * K_ + lane] : 0.f;
            // on-chain stub: i = 0..7 via readlane
            float a0 = readlane_f<0>(p) * Ecol[0];
            float a1 = readlane_f<1>(p) * Ecol[1];
            float a2 = readlane_f<2>(p) * Ecol[2];
            float a3 = readlane_f<3>(p) * Ecol[3];
            a0 = fmaf(readlane_f<4>(p), Ecol[4], a0);
            a1 = fmaf(readlane_f<5>(p), Ecol[5], a1);
            a2 = fmaf(readlane_f<6>(p), Ecol[6], a2);
            a3 = fmaf(readlane_f<7>(p), Ecol[7], a3);
            // pre-loaded exchange: i = 8..63, plain VGPR fma (no SGPR, no wait)
#pragma unroll
            for (int k = 0; k < 14; ++k) {
                a0 = fmaf(Lp[k].x, Ecol[8 + 4 * k + 0], a0);
                a1 = fmaf(Lp[k].y, Ecol[8 + 4 * k + 1], a1);
                a2 = fmaf(Lp[k].z, Ecol[8 + 4 * k + 2], a2);
                a3 = fmaf(Lp[k].w, Ecol[8 + 4 * k + 3], a3);
            }
            float D = (a0 + a1) + (a2 + a3);
            float pnew = D * xg;         // only on-chain op after the dot
            if (t < seq_len) { p = pnew; C += en0 + logD0prev; }
            // publish p_t, immediately issue step-(t+1) reads (off-chain:
            // consumed only after next iteration's prep + readlane stub)
            pexch[lane] = p;
#pragma unroll
            for (int k = 0; k < 14; ++k)
                Lp[k] = *(const float4*)&pexch[8 + 4 * k];
            // off-chain prep for next step
            float D0 = readlane0_f(D);
            logD0prev = __logf(D0);
            float gn = __fdividef(1.f, D0);
            en0 = readlane0_f(e_f);
            xg = __expf(e_f - en0) * gn;
        }
        float rs = p;
#pragma unroll
        for (int m = 32; m; m >>= 1) rs += __shfl_xor(rs, m, 64);
        float log_norm = C + __logf(rs);

        // ---------------- sequence score ----------------
        float sc = 0.f;
#pragma unroll
        for (int k = 0; k < 4; ++k) {
            int t = lane + k * 64;
            if (t < seq_len) {
                int tg = target[b * T_ + t];
                sc += ebuf[t * K_ + tg];
                if (t >= 1) sc += trans[target[b * T_ + t - 1] * K_ + tg];
            }
        }
#pragma unroll
        for (int m = 32; m; m >>= 1) sc += __shfl_xor(sc, m, 64);
        if (lane == 0) out[BT_ + b] = sc - log_norm;
    } else {
        // ================= Viterbi (wave 1): pipelined max-plus =============
        float Tcol[64];
#pragma unroll
        for (int i = 0; i < 64; ++i) Tcol[i] = trans[i * K_ + lane];
        for (int idx = lane; idx < K_ * K_; idx += 64)
            tbuf[(idx >> 6) * 65 + (idx & 63)] = trans[idx];

        float v = ebuf[lane];
        vbuf[lane] = v;                  // history write == exchange publish
        float4 Lv[14];
#pragma unroll
        for (int k = 0; k < 14; ++k) Lv[k] = ((const float4*)&vbuf[0])[2 + k];
        float e_n = ebuf[K_ + lane];

        for (int t = 1; t < T_; ++t) {
            float e_f = (t < T_ - 1) ? ebuf[(t + 1) * K_ + lane] : 0.f;
            // on-chain stub: i = 0..7 via readlane
            float m0 = readlane_f<0>(v) + Tcol[0];
            float m1 = readlane_f<1>(v) + Tcol[1];
            float m2 = readlane_f<2>(v) + Tcol[2];
            float m3 = readlane_f<3>(v) + Tcol[3];
            m0 = fmaxf(m0, readlane_f<4>(v) + Tcol[4]);
            m1 = fmaxf(m1, readlane_f<5>(v) + Tcol[5]);
            m2 = fmaxf(m2, readlane_f<6>(v) + Tcol[6]);
            m3 = fmaxf(m3, readlane_f<7>(v) + Tcol[7]);
            // pre-loaded exchange: i = 8..63
#pragma unroll
            for (int k = 0; k < 14; ++k) {
                m0 = fmaxf(m0, Lv[k].x + Tcol[8 + 4 * k + 0]);
                m1 = fmaxf(m1, Lv[k].y + Tcol[8 + 4 * k + 1]);
                m2 = fmaxf(m2, Lv[k].z + Tcol[8 + 4 * k + 2]);
                m3 = fmaxf(m3, Lv[k].w + Tcol[8 + 4 * k + 3]);
            }
            float M = fmaxf(fmaxf(m0, m1), fmaxf(m2, m3));
            float vn = M + e_n;
            if (t < seq_len) v = vn;
            // publish row t (history AND exchange), issue step-(t+1) reads
            vbuf[t * K_ + lane] = v;
            const float4* vrow = (const float4*)&vbuf[t * K_];
#pragma unroll
            for (int k = 0; k < 14; ++k) Lv[k] = vrow[2 + k];
            e_n = e_f;
        }

        // last tag: first index of max over lanes (np.argmax tie rule)
        float M = wave_max64(v);
        unsigned long long ball = __ballot(v >= M);
        int tag = (int)__builtin_ctzll(ball);

        int path[4];
#pragma unroll
        for (int k = 0; k < 4; ++k) path[k] = 0;
        if (lane == ((T_ - 1) & 63)) path[(T_ - 1) >> 6] = tag;

        float vpre = vbuf[(T_ - 2) * K_ + lane];
        for (int t = T_ - 1; t >= 1; --t) {
            float vnext = (t >= 2) ? vbuf[(t - 2) * K_ + lane] : 0.f;
            if (t < seq_len) {
                float s = vpre + tbuf[lane * 65 + tag];
                float Ms = wave_max64(s);
                unsigned long long bl = __ballot(s >= Ms);
                tag = (int)__builtin_ctzll(bl);
            }
            int pidx = t - 1;
            if (lane == (pidx & 63)) path[pidx >> 6] = tag;
            vpre = vnext;
        }
#pragma unroll
        for (int k = 0; k < 4; ++k) {
            int t = lane + k * 64;
            out[b * T_ + t] = (t < seq_len) ? (float)path[k] : 0.f;
        }
    }
}

// ---------------------------------------------------------------------------
extern "C" void kernel_launch(void* const* d_in, const int* in_sizes, int n_in,
                              void* d_out, int out_size, void* d_ws, size_t ws_size,
                              hipStream_t stream) {
    const float* hidden = (const float*)d_in[0];
    const int* masks    = (const int*)d_in[1];
    const int* target   = (const int*)d_in[2];
    const float* W      = (const float*)d_in[3];
    const float* bias   = (const float*)d_in[4];
    const float* trans  = (const float*)d_in[5];
    float* out = (float*)d_out;
    float* emis = (float*)d_ws;

    gemm_emis<<<dim3(BT_ / BM_), dim3(256), 0, stream>>>(hidden, W, bias, emis);
    crf_kernel<<<dim3(B_), dim3(128), 0, stream>>>(emis, masks, target, trans, out);
}